// Round 1
// baseline (24159.033 us; speedup 1.0000x reference)
//
#include <hip/hip_runtime.h>

// LSTM: B=8192, T=2048, D=1, H=256, C=10
// Persistent kernel: 256 WGs x 1024 threads (one per CU), 32 batch rows per WG.
// Recurrent GEMM per step: (32 x 256) @ (256 x 1024) via v_mfma_f32_16x16x32_f16.
// Weight residency split along K: k[0,64) in VGPRs, k[64,128) in LDS (128 KB),
// k[128,256) streamed from L2 each step (frag-ordered, coalesced 16B/lane).
// h tile lives in LDS (single buffer, 2 barriers/step); c persists in registers.
// d_ws layout: 512 KB of fp16 B-fragments, byte off = ((kk*16+w)*4+t)*1024 + lane*16.

#define BB 8192
#define TT 2048
#define HH 256
#define CC 10

typedef _Float16 half8 __attribute__((ext_vector_type(8)));
typedef float float4v __attribute__((ext_vector_type(4)));

#define LDS_W_BYTES   131072                 // k in [64,128): 2 kk-groups * 64 KB
#define LDS_H_OFF     LDS_W_BYTES
#define H_STRIDE      264                    // 256 + 8 fp16 pad (A-reads 2-way free)
#define LDS_H_BYTES   (32 * H_STRIDE * 2)    // 16896
#define LDS_XS_OFF    (LDS_H_OFF + LDS_H_BYTES)
#define LDS_TOTAL     (LDS_XS_OFF + 32 * 4)  // 148096 bytes

__device__ __forceinline__ float frcp(float v) {
#if __has_builtin(__builtin_amdgcn_rcpf)
    return __builtin_amdgcn_rcpf(v);
#else
    return 1.0f / v;
#endif
}
__device__ __forceinline__ float fsig(float v)  { return frcp(1.0f + __expf(-v)); }
__device__ __forceinline__ float ftanh(float v) { return 2.0f * frcp(1.0f + __expf(-2.0f * v)) - 1.0f; }

// Pack W_{g,i,f,o}h (fp32 [256][256], row k, col j) into fp16 MFMA B-fragment order.
// 16B-unit u = ((kk*16 + w)*4 + t)*64 + lane ; element j: k = kk*32 + (lane>>4)*8 + j,
// n-col = gate t, hidden j_h = w*16 + (lane&15).
__global__ void pack_weights(const float* __restrict__ Wg, const float* __restrict__ Wi,
                             const float* __restrict__ Wf, const float* __restrict__ Wo,
                             _Float16* __restrict__ wsW) {
    int u = blockIdx.x * blockDim.x + threadIdx.x;   // 32768 units total
    int kk = u >> 12, rem = u & 4095;
    int w = rem >> 8, rem2 = rem & 255;
    int t = rem2 >> 6, lane = rem2 & 63;
    int q = lane >> 4, l15 = lane & 15;
    int jh = w * 16 + l15;
    const float* Wsrc = (t == 0) ? Wg : (t == 1) ? Wi : (t == 2) ? Wf : Wo;
    half8 v;
#pragma unroll
    for (int j = 0; j < 8; ++j) {
        int k = kk * 32 + q * 8 + j;
        v[j] = (_Float16)Wsrc[k * HH + jh];
    }
    ((half8*)wsW)[u] = v;
}

__global__ __launch_bounds__(1024) void lstm_main(
    const float* __restrict__ x, const _Float16* __restrict__ wsW,
    const float* __restrict__ Wgx, const float* __restrict__ Wix,
    const float* __restrict__ Wfx, const float* __restrict__ Wox,
    const float* __restrict__ bg, const float* __restrict__ bi,
    const float* __restrict__ bfp, const float* __restrict__ bo,
    const float* __restrict__ Wp, const float* __restrict__ bp,
    float* __restrict__ out)
{
    extern __shared__ char smem[];
    _Float16* Wlds = (_Float16*)smem;
    _Float16* hbuf = (_Float16*)(smem + LDS_H_OFF);
    float*    xs   = (float*)(smem + LDS_XS_OFF);

    const int tid = threadIdx.x;
    const int w   = tid >> 6;
    const int lane = tid & 63;
    const int q   = lane >> 4;
    const int l15 = lane & 15;
    const int jh  = w * 16 + l15;        // this lane's hidden column
    const int b0  = blockIdx.x * 32;

    // ---- prologue ----
    for (int i = tid; i < 32 * H_STRIDE; i += 1024) hbuf[i] = (_Float16)0.f;   // h0 = 0
    if (tid < 32) xs[tid] = x[(b0 + tid) * TT + 0];
    {   // stage k[64,128) weight frags into LDS (layout preserved from d_ws)
        const uint4* src = (const uint4*)((const char*)wsW + 2 * 65536);
        uint4* dst = (uint4*)Wlds;
        for (int i = tid; i < LDS_W_BYTES / 16; i += 1024) dst[i] = src[i];
    }
    const char* wl = (const char*)wsW + w * 4096 + lane * 16;   // per-lane frag base
    half8 wr[8];                                                // k[0,64) resident: 32 VGPRs
#pragma unroll
    for (int kk = 0; kk < 2; ++kk)
#pragma unroll
        for (int tt = 0; tt < 4; ++tt)
            wr[kk * 4 + tt] = *(const half8*)(wl + kk * 65536 + tt * 1024);

    float wxv[4] = { Wgx[jh], Wix[jh], Wfx[jh], Wox[jh] };
    float bv[4]  = { bg[jh],  bi[jh],  bfp[jh], bo[jh]  };
    float4v cst[2]; cst[0] = (float4v){0.f,0.f,0.f,0.f}; cst[1] = (float4v){0.f,0.f,0.f,0.f};
    __syncthreads();

    // ---- time loop ----
#pragma unroll 1
    for (int ts = 0; ts < TT; ++ts) {
        // stream k[128,192) now; k[192,256) groups reloaded mid K-loop
        half8 st[2][4];
#pragma unroll
        for (int tt = 0; tt < 4; ++tt) st[0][tt] = *(const half8*)(wl + 4 * 65536 + tt * 1024);
#pragma unroll
        for (int tt = 0; tt < 4; ++tt) st[1][tt] = *(const half8*)(wl + 5 * 65536 + tt * 1024);

        // prefetch next x early (global latency hidden under K-loop)
        float xnext = 0.f;
        int tn = (ts + 1 < TT) ? (ts + 1) : (TT - 1);
        if (tid < 32) xnext = x[(b0 + tid) * TT + tn];

        // acc init = bias + x_t * W_x  (fp32 path, exact)
        float4v acc[2][4];
#pragma unroll
        for (int mt = 0; mt < 2; ++mt) {
            float xv[4];
#pragma unroll
            for (int r = 0; r < 4; ++r) xv[r] = xs[mt * 16 + q * 4 + r];
#pragma unroll
            for (int tt = 0; tt < 4; ++tt)
#pragma unroll
                for (int r = 0; r < 4; ++r)
                    acc[mt][tt][r] = bv[tt] + xv[r] * wxv[tt];
        }

        // K loop: 8 kk-groups of 32, A = h from LDS, B from regs/LDS/stream
#pragma unroll
        for (int kk = 0; kk < 8; ++kk) {
            half8 a0 = *(const half8*)(hbuf + l15 * H_STRIDE + kk * 32 + q * 8);
            half8 a1 = *(const half8*)(hbuf + (l15 + 16) * H_STRIDE + kk * 32 + q * 8);
#pragma unroll
            for (int tt = 0; tt < 4; ++tt) {
                half8 bfrag;
                if (kk < 2)      bfrag = wr[kk * 4 + tt];
                else if (kk < 4) bfrag = *(const half8*)((const char*)Wlds +
                                        (kk - 2) * 65536 + w * 4096 + tt * 1024 + lane * 16);
                else             bfrag = st[kk & 1][tt];
                acc[0][tt] = __builtin_amdgcn_mfma_f32_16x16x32_f16(a0, bfrag, acc[0][tt], 0, 0, 0);
                acc[1][tt] = __builtin_amdgcn_mfma_f32_16x16x32_f16(a1, bfrag, acc[1][tt], 0, 0, 0);
            }
            if (kk == 4) {
#pragma unroll
                for (int tt = 0; tt < 4; ++tt) st[0][tt] = *(const half8*)(wl + 6 * 65536 + tt * 1024);
            }
            if (kk == 5) {
#pragma unroll
                for (int tt = 0; tt < 4; ++tt) st[1][tt] = *(const half8*)(wl + 7 * 65536 + tt * 1024);
            }
        }

        // gates + state update (lane owns (b = mt*16+q*4+r, j = jh))
        _Float16 hn16[2][4];
#pragma unroll
        for (int mt = 0; mt < 2; ++mt) {
#pragma unroll
            for (int r = 0; r < 4; ++r) {
                float g  = ftanh(acc[mt][0][r]);
                float ii = fsig (acc[mt][1][r]);
                float f  = fsig (acc[mt][2][r]);
                float o  = fsig (acc[mt][3][r]);
                float cn = g * ii + cst[mt][r] * f;
                cst[mt][r] = cn;
                hn16[mt][r] = (_Float16)(ftanh(cn) * o);
            }
        }

        __syncthreads();   // B1: all A-frag reads of h done
#pragma unroll
        for (int mt = 0; mt < 2; ++mt)
#pragma unroll
            for (int r = 0; r < 4; ++r)
                hbuf[(mt * 16 + q * 4 + r) * H_STRIDE + jh] = hn16[mt][r];
        if (tid < 32) xs[tid] = xnext;
        __syncthreads();   // B2: h_new visible for next step
    }

    // ---- epilogue: out = h_T @ W_ph + b_p ; wave w handles rows 2w, 2w+1 ----
#pragma unroll
    for (int rr = 0; rr < 2; ++rr) {
        int b = w * 2 + rr;
        float hv[4];
#pragma unroll
        for (int a = 0; a < 4; ++a) hv[a] = (float)hbuf[b * H_STRIDE + lane + a * 64];
#pragma unroll
        for (int c = 0; c < CC; ++c) {
            float s = 0.f;
#pragma unroll
            for (int a = 0; a < 4; ++a) s += hv[a] * Wp[(lane + a * 64) * CC + c];
#pragma unroll
            for (int off = 32; off > 0; off >>= 1) s += __shfl_xor(s, off, 64);
            if (lane == 0) out[(b0 + b) * CC + c] = s + bp[c];
        }
    }
}

extern "C" void kernel_launch(void* const* d_in, const int* in_sizes, int n_in,
                              void* d_out, int out_size, void* d_ws, size_t ws_size,
                              hipStream_t stream) {
    (void)in_sizes; (void)n_in; (void)out_size; (void)ws_size; // needs ws_size >= 524288
    const float* x   = (const float*)d_in[0];
    const float* Wgx = (const float*)d_in[1];
    const float* Wgh = (const float*)d_in[2];
    const float* Wix = (const float*)d_in[3];
    const float* Wih = (const float*)d_in[4];
    const float* Wfx = (const float*)d_in[5];
    const float* Wfh = (const float*)d_in[6];
    const float* Wox = (const float*)d_in[7];
    const float* Woh = (const float*)d_in[8];
    const float* Wp  = (const float*)d_in[9];
    const float* bg  = (const float*)d_in[10];
    const float* bi  = (const float*)d_in[11];
    const float* bf  = (const float*)d_in[12];
    const float* bo  = (const float*)d_in[13];
    const float* bp  = (const float*)d_in[14];
    _Float16* wsW = (_Float16*)d_ws;

    pack_weights<<<128, 256, 0, stream>>>(Wgh, Wih, Wfh, Woh, wsW);

    hipFuncSetAttribute((const void*)lstm_main,
                        hipFuncAttributeMaxDynamicSharedMemorySize, LDS_TOTAL);
    lstm_main<<<256, 1024, LDS_TOTAL, stream>>>(
        x, wsW, Wgx, Wix, Wfx, Wox, bg, bi, bf, bo, Wp, bp, (float*)d_out);
}